// Round 4
// baseline (1061.819 us; speedup 1.0000x reference)
//
#include <hip/hip_runtime.h>
#include <hip/hip_bf16.h>

#define NN 50000
#define NE 800000
#define NA (NE + NN)
#define NH 8
#define NC 16
#define ND 128
#define NHID 64
#define NSH 64
#define NOUT 40
#define BN_EPS 1e-5

#define WOFF (NN * NOUT)
#define LOFF (WOFF + NE)
#define NIN 27
#define NCV 22

static inline int ceil_div(int a, int b) { return (a + b - 1) / b; }

typedef __hip_bfloat16 bf16;
__device__ inline float b2f(bf16 v) { return __bfloat162float(v); }

typedef short bf16x8v __attribute__((ext_vector_type(8)));
typedef float f32x4v __attribute__((ext_vector_type(4)));

struct Ptrs { const void* p[NIN]; int n[NIN]; };
struct ConvTab { int src[NCV]; int dstOff[NCV]; int n[NCV]; };
struct SplitTab { int srcOff[5]; int dstOff[5]; int n[5]; };

__global__ void sent_k(float* out, float v) { out[0] = v; }

// exact 3-way bf16 split: v = b0 + b1 + b2 + eps, |eps| <= 2^-27 |v|
__device__ inline void split3(float v, ushort* o0, ushort* o1, ushort* o2) {
    bf16 h0 = __float2bfloat16(v);
    float r1 = v - __bfloat162float(h0);
    bf16 h1 = __float2bfloat16(r1);
    float r2 = r1 - __bfloat162float(h1);
    bf16 h2 = __float2bfloat16(r2);
    __builtin_memcpy(o0, &h0, 2);
    __builtin_memcpy(o1, &h1, 2);
    __builtin_memcpy(o2, &h2, 2);
}
__device__ inline short f2bs(float v) {
    bf16 h = __float2bfloat16(v);
    short s;
    __builtin_memcpy(&s, &h, 2);
    return s;
}

// ---------- dtype detection (fp32 vs bf16; int32 vs int64) ----------
__global__ __launch_bounds__(64) void detect_k(Ptrs P, int* flags) {
    int b = blockIdx.x, lane = threadIdx.x;
    const void* p = P.p[b];
    int n = P.n[b];
    if (b == 1) {
        const int* w = (const int*)p;
        int m = n < 256 ? n : 256;
        int oddNz = 0;
        for (int i = lane; i < m; i += 64)
            if ((i & 1) && w[i] != 0) oddNz = 1;
        unsigned long long any = __ballot(oddNz);
        if (lane == 0) flags[1] = (any == 0ULL) ? 1 : 0;   // 1 => int64
        return;
    }
    int m = n < 256 ? n : 256;
    const bf16* hb = (const bf16*)p;
    int impl = 0, evenNz = 0, oddNz = 0;
    for (int i = lane; i < m; i += 64) {
        float v = b2f(hb[i]);
        bool bad = !isfinite(v) || fabsf(v) > 64.0f || (v != 0.0f && fabsf(v) < 1e-6f);
        if (bad) impl++;
        if (v != 0.0f) { if (i & 1) oddNz = 1; else evenNz = 1; }
    }
#pragma unroll
    for (int off = 32; off > 0; off >>= 1) impl += __shfl_down(impl, off, 64);
    unsigned long long be = __ballot(evenNz), bo = __ballot(oddNz);
    if (lane == 0) {
        int thresh = (m >= 8) ? (m / 8) : 1;
        int isF32 = 0;
        if (impl >= thresh) isF32 = 1;
        else if (be == 0ULL && bo != 0ULL) isF32 = 1;
        flags[b] = isF32;
    }
}

__global__ __launch_bounds__(256) void conv_f_k(const void* __restrict__ src,
                                                const int* __restrict__ flags, int fi,
                                                float* __restrict__ dst, int n) {
    int i = blockIdx.x * 256 + threadIdx.x;
    if (i >= n) return;
    dst[i] = flags[fi] ? ((const float*)src)[i] : b2f(((const bf16*)src)[i]);
}

__global__ __launch_bounds__(256) void conv_all_k(Ptrs P, ConvTab T,
                                                  const int* __restrict__ flags,
                                                  float* __restrict__ wa) {
    int b = blockIdx.x;
    const void* src = P.p[T.src[b]];
    int isf = flags[T.src[b]];
    float* dst = wa + T.dstOff[b];
    int n = T.n[b];
    for (int i = threadIdx.x; i < n; i += 256)
        dst[i] = isf ? ((const float*)src)[i] : b2f(((const bf16*)src)[i]);
}

// repack Ws1 [64][256] -> fused [128][128]
__global__ __launch_bounds__(256) void repack_ws1_k(const float* __restrict__ s,
                                                    float* __restrict__ d) {
    int id = blockIdx.x * 256 + threadIdx.x;
    if (id >= 128 * 128) return;
    int m = id >> 7, k = id & 127;
    d[id] = (m < 64) ? s[m * 256 + k] : s[(m - 64) * 256 + 128 + k];
}

// split the 5 MFMA weight matrices into 3 bf16 planes each
__global__ __launch_bounds__(256) void split_w_k(const float* __restrict__ wa,
                                                 SplitTab T, ushort* __restrict__ wb) {
    int id = blockIdx.x * 256 + threadIdx.x;
    for (int m = 0; m < 5; ++m) {
        if (id < T.n[m]) {
            float v = wa[T.srcOff[m] + id];
            ushort b0, b1, b2;
            split3(v, &b0, &b1, &b2);
            ushort* d = wb + T.dstOff[m];
            d[id] = b0;
            d[T.n[m] + id] = b1;
            d[2 * T.n[m] + id] = b2;
            return;
        }
        id -= T.n[m];
    }
}

__global__ __launch_bounds__(256) void conv_i_k(const void* __restrict__ src,
                                                const int* __restrict__ flags,
                                                int* __restrict__ dst, int n) {
    int i = blockIdx.x * 256 + threadIdx.x;
    if (i >= n) return;
    const int* s = (const int*)src;
    dst[i] = flags[1] ? s[2 * i] : s[i];
}

__global__ __launch_bounds__(256) void check_k(const int* __restrict__ ei, int* err) {
    int i = blockIdx.x * 256 + threadIdx.x;
    if (i < 2 * NE && (unsigned)ei[i] >= NN) atomicOr(err, 1);
}
__global__ void finalize_k(const int* err, float* out) {
    if (*err) out[0] = 800.0f;
}

// ---------- ordered-key mapping for fp64 atomic max ----------
__device__ inline unsigned long long d2key(double v) {
    unsigned long long b = __double_as_longlong(v);
    return (b & 0x8000000000000000ULL) ? ~b : (b | 0x8000000000000000ULL);
}
__device__ inline double key2d(unsigned long long k) {
    return (k & 0x8000000000000000ULL) ? __longlong_as_double(k & 0x7fffffffffffffffULL)
                                       : __longlong_as_double(~k);
}

// ---------- CSR build ----------
__global__ __launch_bounds__(256) void deg_dst_k(const int* __restrict__ ei, int* deg) {
    int e = blockIdx.x * 256 + threadIdx.x;
    if (e >= NA) return;
    int d = (e < NE) ? ei[NE + e] : e - NE;
    if ((unsigned)d < NN) atomicAdd(&deg[d], 1);
}
__global__ __launch_bounds__(256) void deg_row_k(const int* __restrict__ ei, int* deg) {
    int e = blockIdx.x * 256 + threadIdx.x;
    if (e >= NE) return;
    int r = ei[e];
    if ((unsigned)r < NN) atomicAdd(&deg[r], 1);
}

__global__ __launch_bounds__(256) void scan1_k(const int* __restrict__ deg,
                                               int* __restrict__ offs,
                                               int* __restrict__ bsums, int n) {
    __shared__ int sh[256];
    int i = blockIdx.x * 256 + threadIdx.x;
    int v = (i < n) ? deg[i] : 0;
    sh[threadIdx.x] = v;
    __syncthreads();
    int acc = v;
    for (int off = 1; off < 256; off <<= 1) {
        int t = (threadIdx.x >= off) ? sh[threadIdx.x - off] : 0;
        __syncthreads();
        acc += t;
        sh[threadIdx.x] = acc;
        __syncthreads();
    }
    if (i < n) offs[i] = acc - v;
    if (threadIdx.x == 255) bsums[blockIdx.x] = acc;
}
__global__ __launch_bounds__(256) void scan2_k(int* __restrict__ bsums, int nb) {
    __shared__ int sh[256];
    int t = threadIdx.x;
    int v = (t < nb) ? bsums[t] : 0;
    sh[t] = v;
    __syncthreads();
    int acc = v;
    for (int off = 1; off < 256; off <<= 1) {
        int x = (t >= off) ? sh[t - off] : 0;
        __syncthreads();
        acc += x;
        sh[t] = acc;
        __syncthreads();
    }
    if (t < nb) bsums[t] = acc - v;
    if (t == nb - 1) bsums[nb] = acc;
}
__global__ __launch_bounds__(256) void scan3_k(int* __restrict__ offs,
                                               const int* __restrict__ bsums, int n, int nb) {
    int i = blockIdx.x * 256 + threadIdx.x;
    if (i < n) offs[i] += bsums[blockIdx.x];
    else if (i == n) offs[n] = bsums[nb];
}
__global__ __launch_bounds__(256) void copy_k(const int* __restrict__ a, int* __restrict__ b,
                                              int n) {
    int i = blockIdx.x * 256 + threadIdx.x;
    if (i < n) b[i] = a[i];
}

__global__ __launch_bounds__(256) void scat_dst_k(const int* __restrict__ ei, int* cur,
                                                  int* __restrict__ entS,
                                                  int* __restrict__ entD) {
    int e = blockIdx.x * 256 + threadIdx.x;
    if (e >= NA) return;
    int s, d;
    if (e < NE) { s = ei[e]; d = ei[NE + e]; }
    else        { s = d = e - NE; }
    if ((unsigned)s >= NN || (unsigned)d >= NN) return;
    int pos = atomicAdd(&cur[d], 1);
    entS[pos] = s;
    entD[pos] = d;
}
__global__ __launch_bounds__(256) void scat_row_k(const int* __restrict__ ei, int* cur,
                                                  int* __restrict__ entc,
                                                  int* __restrict__ ente) {
    int e = blockIdx.x * 256 + threadIdx.x;
    if (e >= NE) return;
    int r = ei[e], c = ei[NE + e];
    if ((unsigned)r >= NN || (unsigned)c >= NN) return;
    int pos = atomicAdd(&cur[r], 1);
    entc[pos] = c;
    ente[pos] = e;
}

// ---------- bf16x3-split MFMA GEMM, W-resident-in-LDS, X-in-registers ----------
// Y[nrows x M] = X[nrows x K] @ W[M x K]^T.  512 threads = 8 waves; wave w owns
// rows (w&3)*16..+16 of a 64-row tile and cols (w>>2)*(M/2)..+(M/2).
// W (3 bf16 planes) is staged ONCE per block into LDS (row stride 272B -> <=2-way
// free bank aliasing); the block then grid-strides over 64-row tiles. X is loaded
// per-lane straight from global (16 rows x 128B contiguous per wave per chunk =
// coalesced), transformed (ADD2/BN/act) and split3'd in registers -> the main loop
// has NO barriers (non-ATT) and no X LDS round-trip.
// Numerics identical to round 3: hi=mfma(a0,w0) flushed to f64 per 32-K chunk;
// lo-chain a0w1,a1w0,a0w2,a1w1,a2w0 kept fp32 (2^-8-scaled). C/D layout PROBED at
// runtime (self-consistent under lane relabeling).
template <int M, int K, bool ADD2, int XBN, bool ATT>
__global__ __launch_bounds__(512, 2) void gemm_bf16_k(const float* __restrict__ X,
                                                      const float* __restrict__ X2,
                                                      const float2* __restrict__ ssX,
                                                      const ushort* __restrict__ Wb,
                                                      const float* __restrict__ bias,
                                                      float* __restrict__ Y, int nrows,
                                                      int ntiles,
                                                      const float* __restrict__ asw,
                                                      const float* __restrict__ adw,
                                                      double* __restrict__ a_src,
                                                      double* __restrict__ a_dst,
                                                      unsigned long long* __restrict__ keyM) {
    static_assert(K == 128, "K must be 128");
    static_assert(!ATT || M == 128, "ATT epilogue requires M==128");
    constexpr int TW = M / 32;            // 16x16 tiles per wave
    constexpr int LP = K + 8;             // padded LDS row: 272B = 17x16B
    constexpr int SZW = 3 * M * LP * 2;   // W planes bytes

    extern __shared__ char smem[];
    ushort* Wsm = (ushort*)smem;
    float2* ssS = (float2*)(smem + SZW);
    double* redS = (double*)(smem + SZW + K * 8);
    double* redD = redS + NH * 16;

    const int t = threadIdx.x;
    const int l = t & 63, wv = t >> 6;
    const int rg = wv & 3;                // row group (16 rows)
    const int ch = wv >> 2;               // col half
    const int lr = l & 15;
    const int lk = l >> 4;
    const int colbase = ch * (M / 2);

    // ---- stage W planes once ----
    {
        constexpr int OCT = (M * K) / 8;
        for (int p = 0; p < 3; ++p)
            for (int idx = t; idx < OCT; idx += 512) {
                int m = idx >> 4;             // K/8 = 16 octets per row
                int ko = (idx & 15) * 8;
                *(uint4*)&Wsm[((size_t)p * M + m) * LP + ko] =
                    *(const uint4*)&Wb[(size_t)p * (M * K) + (size_t)m * K + ko];
            }
    }
    if constexpr (XBN != 0) {
        for (int i = t; i < K; i += 512) ssS[i] = ssX[i];
    }
    __syncthreads();

    const f32x4v zz = {0.0f, 0.0f, 0.0f, 0.0f};

    // ---- runtime C/D layout probe (2 MFMAs) ----
    int rowD[4], colD[4];
    {
        bf16x8v pLr = {0, 0, 0, 0, 0, 0, 0, 0};
        bf16x8v pOne = pLr;
        if (lk == 0) {
            pLr[0] = f2bs((float)lr);
            pOne[0] = f2bs(1.0f);
        }
        f32x4v dr = __builtin_amdgcn_mfma_f32_16x16x32_bf16(pLr, pOne, zz, 0, 0, 0);
        f32x4v dc = __builtin_amdgcn_mfma_f32_16x16x32_bf16(pOne, pLr, zz, 0, 0, 0);
#pragma unroll
        for (int r = 0; r < 4; ++r) {
            rowD[r] = (int)dr[r];
            colD[r] = (int)dc[r];
        }
    }

    for (int tile = blockIdx.x; tile < ntiles; tile += gridDim.x) {
        const int row0 = tile * 64;
        const int xrow = row0 + rg * 16 + lr;
        const bool rowok = xrow < nrows;
        const float* xp = X + (size_t)xrow * K;

        f32x4v hi[TW], lo[TW];
        double acc[TW][4];
#pragma unroll
        for (int tt = 0; tt < TW; ++tt) {
            hi[tt] = zz;
            lo[tt] = zz;
#pragma unroll
            for (int i = 0; i < 4; ++i) acc[tt][i] = 0.0;
        }

#pragma unroll
        for (int kc = 0; kc < K / 32; ++kc) {
            const int kb = kc * 32 + lk * 8;
            float xv[8];
#pragma unroll
            for (int j = 0; j < 8; ++j) xv[j] = 0.0f;
            if (rowok) {
                float4 va = *(const float4*)(xp + kb);
                float4 vb = *(const float4*)(xp + kb + 4);
                xv[0] = va.x; xv[1] = va.y; xv[2] = va.z; xv[3] = va.w;
                xv[4] = vb.x; xv[5] = vb.y; xv[6] = vb.z; xv[7] = vb.w;
                if constexpr (ADD2) {
                    const float* xp2 = X2 + (size_t)xrow * K;
                    float4 wa2 = *(const float4*)(xp2 + kb);
                    float4 wb2 = *(const float4*)(xp2 + kb + 4);
                    xv[0] += wa2.x; xv[1] += wa2.y; xv[2] += wa2.z; xv[3] += wa2.w;
                    xv[4] += wb2.x; xv[5] += wb2.y; xv[6] += wb2.z; xv[7] += wb2.w;
                }
                if constexpr (XBN != 0) {
#pragma unroll
                    for (int j = 0; j < 8; ++j) {
                        float2 s = ssS[kb + j];
                        float v = xv[j] * s.x + s.y;
                        xv[j] = (XBN == 1) ? (v > 0.0f ? v : expm1f(v))
                                           : (v > 0.0f ? v : 0.0f);
                    }
                }
            }
            ushort u0[8], u1[8], u2[8];
#pragma unroll
            for (int j = 0; j < 8; ++j) split3(xv[j], &u0[j], &u1[j], &u2[j]);
            bf16x8v A0, A1, A2;
#pragma unroll
            for (int j = 0; j < 8; ++j) {
                A0[j] = (short)u0[j];
                A1[j] = (short)u1[j];
                A2[j] = (short)u2[j];
            }

#pragma unroll
            for (int tt = 0; tt < TW; ++tt) {
                const int bc = colbase + tt * 16 + lr;
                bf16x8v B0 = *(const bf16x8v*)&Wsm[((size_t)0 * M + bc) * LP + kb];
                bf16x8v B1 = *(const bf16x8v*)&Wsm[((size_t)1 * M + bc) * LP + kb];
                bf16x8v B2 = *(const bf16x8v*)&Wsm[((size_t)2 * M + bc) * LP + kb];
                hi[tt] = __builtin_amdgcn_mfma_f32_16x16x32_bf16(A0, B0, hi[tt], 0, 0, 0);
                lo[tt] = __builtin_amdgcn_mfma_f32_16x16x32_bf16(A0, B1, lo[tt], 0, 0, 0);
                lo[tt] = __builtin_amdgcn_mfma_f32_16x16x32_bf16(A1, B0, lo[tt], 0, 0, 0);
                lo[tt] = __builtin_amdgcn_mfma_f32_16x16x32_bf16(A0, B2, lo[tt], 0, 0, 0);
                lo[tt] = __builtin_amdgcn_mfma_f32_16x16x32_bf16(A1, B1, lo[tt], 0, 0, 0);
                lo[tt] = __builtin_amdgcn_mfma_f32_16x16x32_bf16(A2, B0, lo[tt], 0, 0, 0);
            }
            // flush hi-acc to f64 per K-chunk (same order as round 3)
#pragma unroll
            for (int tt = 0; tt < TW; ++tt) {
#pragma unroll
                for (int i = 0; i < 4; ++i) acc[tt][i] += (double)hi[tt][i];
                hi[tt] = zz;
            }
        }

        // epilogue: add lo, bias, fp32 round, store (probed row/col)
        int rowg[4];
#pragma unroll
        for (int i = 0; i < 4; ++i) rowg[i] = row0 + rg * 16 + rowD[i];

        float yv[TW][4];
#pragma unroll
        for (int tt = 0; tt < TW; ++tt) {
#pragma unroll
            for (int i = 0; i < 4; ++i) {
                int col = colbase + tt * 16 + colD[i];
                double v = acc[tt][i] + (double)lo[tt][i];
                if (bias) v += (double)bias[col];
                yv[tt][i] = (float)v;
                if (rowg[i] < nrows) Y[(size_t)rowg[i] * M + col] = yv[tt][i];
            }
        }

        if constexpr (ATT) {
            // each 16-col tile == one head
#pragma unroll
            for (int tt = 0; tt < TW; ++tt) {
                const int head = (colbase + tt * 16) >> 4;
                double s[4], d[4];
#pragma unroll
                for (int i = 0; i < 4; ++i) {
                    int col = colbase + tt * 16 + colD[i];
                    s[i] = (double)yv[tt][i] * (double)asw[col];
                    d[i] = (double)yv[tt][i] * (double)adw[col];
                }
#pragma unroll
                for (int off = 1; off <= 8; off <<= 1) {
#pragma unroll
                    for (int i = 0; i < 4; ++i) {
                        s[i] += __shfl_xor(s[i], off, 64);
                        d[i] += __shfl_xor(d[i], off, 64);
                    }
                }
                if (lr == 0) {
                    double mS = -1e300, mD = -1e300;
#pragma unroll
                    for (int i = 0; i < 4; ++i) {
                        if (rowg[i] < nrows) {
                            a_src[(size_t)rowg[i] * NH + head] = s[i];
                            a_dst[(size_t)rowg[i] * NH + head] = d[i];
                            if (s[i] > mS) mS = s[i];
                            if (d[i] > mD) mD = d[i];
                        }
                    }
                    redS[head * 16 + rg * 4 + lk] = mS;
                    redD[head * 16 + rg * 4 + lk] = mD;
                }
            }
            __syncthreads();
            if (t < NH) {
                double mS = -1e300, mD = -1e300;
#pragma unroll
                for (int g = 0; g < 16; ++g) {
                    if (redS[t * 16 + g] > mS) mS = redS[t * 16 + g];
                    if (redD[t * 16 + g] > mD) mD = redD[t * 16 + g];
                }
                atomicMax(&keyM[t], d2key(mS));
                atomicMax(&keyM[NH + t], d2key(mD));
            }
            __syncthreads();
        }
    }
}

// ---------- legacy VALU GEMM (kept for the 40-col classifier head) ----------
template <int M, int K, int TC, bool ADD2, int XBN, bool ATT>
__global__ __launch_bounds__(256) void gemm_k(const float* __restrict__ X,
                                              const float* __restrict__ X2,
                                              const float2* __restrict__ ssX,
                                              const float* __restrict__ W, int wstride,
                                              const float* __restrict__ bias,
                                              float* __restrict__ Y, int nrows,
                                              const float* __restrict__ asw,
                                              const float* __restrict__ adw,
                                              double* __restrict__ a_src,
                                              double* __restrict__ a_dst,
                                              unsigned long long* __restrict__ keyM) {
    static_assert(!ATT || TC == 32, "ATT epilogue requires TC==32");
    constexpr int KT = 32;
    constexpr int TR = 256 / TC;
    constexpr int ROWS = TR * 4;          // multiple of 4 -> (ROWS+4)*4B is 16B-aligned
    __shared__ float Ws[KT][M + 4];
    __shared__ float Xs[KT][ROWS + 4];    // transposed tile

    const int t = threadIdx.x;
    const int lane = t & 63, wv = t >> 6;
    const int row0 = blockIdx.x * ROWS;

    double acc[4][4];
#pragma unroll
    for (int i = 0; i < 4; ++i)
#pragma unroll
        for (int j = 0; j < 4; ++j) acc[i][j] = 0.0;

    for (int k0 = 0; k0 < K; k0 += KT) {
        {
            const int mi = lane >> 3, ki = lane & 7;
            for (int b = wv; b < (M / 8) * (KT / 8); b += 4) {
                int bm = b % (M / 8), bk = b / (M / 8);
                int m = bm * 8 + mi, kk = bk * 8 + ki;
                Ws[kk][m] = W[(size_t)m * wstride + k0 + kk];
            }
        }
        for (int idx = t; idx < ROWS * KT; idx += 256) {
            int r = idx / KT, kk = idx % KT;
            int row = row0 + r;
            float v = 0.0f;
            if (row < nrows) {
                v = X[(size_t)row * K + k0 + kk];
                if (ADD2) v += X2[(size_t)row * K + k0 + kk];
                if (XBN) {
                    float2 s = ssX[k0 + kk];
                    v = v * s.x + s.y;
                    if (XBN == 1) v = v > 0.0f ? v : expm1f(v);
                    else          v = v > 0.0f ? v : 0.0f;
                }
            }
            Xs[kk][r] = v;
        }
        __syncthreads();

        if (t < TR * TC) {
            const int c0 = (t % TC) * 4;
            const int r0 = (t / TC) * 4;
            float facc[4][4];
#pragma unroll
            for (int i = 0; i < 4; ++i)
#pragma unroll
                for (int j = 0; j < 4; ++j) facc[i][j] = 0.0f;
#pragma unroll 4
            for (int kk = 0; kk < KT; ++kk) {
                float4 w = *(const float4*)&Ws[kk][c0];
                float4 x4 = *(const float4*)&Xs[kk][r0];
                float xv[4] = {x4.x, x4.y, x4.z, x4.w};
#pragma unroll
                for (int i = 0; i < 4; ++i) {
                    facc[i][0] += xv[i] * w.x;
                    facc[i][1] += xv[i] * w.y;
                    facc[i][2] += xv[i] * w.z;
                    facc[i][3] += xv[i] * w.w;
                }
                if ((kk & 15) == 15) {
#pragma unroll
                    for (int i = 0; i < 4; ++i)
#pragma unroll
                        for (int j = 0; j < 4; ++j) {
                            acc[i][j] += (double)facc[i][j];
                            facc[i][j] = 0.0f;
                        }
                }
            }
        }
        __syncthreads();
    }

    if (t < TR * TC) {
        const int c0 = (t % TC) * 4;
        const int r0 = (t / TC) * 4;
#pragma unroll
        for (int i = 0; i < 4; ++i) {
            int row = row0 + r0 + i;
#pragma unroll
            for (int j = 0; j < 4; ++j) {
                double v = acc[i][j];
                if (bias) v += (double)bias[c0 + j];
                if (row < nrows) Y[(size_t)row * M + c0 + j] = (float)v;
            }
        }
    }
}

// ---------- edge-parallel exp (fp32 expf; x computed fp64) ----------
__global__ __launch_bounds__(256) void edge_exp_k(const int* __restrict__ entS,
                                                  const int* __restrict__ entD,
                                                  const double* __restrict__ a_src,
                                                  const double* __restrict__ a_dst,
                                                  const unsigned long long* __restrict__ keyM,
                                                  float* __restrict__ expv) {
    int id = blockIdx.x * 256 + threadIdx.x;
    if (id >= NA * NH) return;
    int i = id >> 3, hh = id & 7;
    int s = entS[i], d = entD[i];
    double x = a_src[(size_t)s * NH + hh] + a_dst[(size_t)d * NH + hh];
    x = x > 0.0 ? x : 0.2 * x;
    double M = key2d(keyM[hh]) + key2d(keyM[NH + hh]);
    if (M < 0.0) M = 0.0;
    expv[id] = expf((float)(x - M));
}

// ---------- GAT gather: wave per dst, float2 feature packing, unroll-4 ----------
__global__ __launch_bounds__(256) void gat_gather_k(const int* __restrict__ offs,
                                                    const int* __restrict__ ent,
                                                    const float* __restrict__ h,
                                                    const float* __restrict__ expv,
                                                    float* __restrict__ outb) {
    int wv = (blockIdx.x * 256 + threadIdx.x) >> 6;
    int lane = threadIdx.x & 63;
    if (wv >= NN) return;
    const int s0 = offs[wv], s1 = offs[wv + 1];
    const int hh = lane >> 3;
    double acc0 = 0.0, acc1 = 0.0, den = 0.0;
    int i = s0;
    for (; i + 4 <= s1; i += 4) {
        int sA = ent[i], sB = ent[i + 1], sC = ent[i + 2], sD = ent[i + 3];
        float eA = expv[(size_t)(i + 0) * NH + hh];
        float eB = expv[(size_t)(i + 1) * NH + hh];
        float eC = expv[(size_t)(i + 2) * NH + hh];
        float eD = expv[(size_t)(i + 3) * NH + hh];
        float2 a = *(const float2*)&h[(size_t)sA * ND + 2 * lane];
        float2 b = *(const float2*)&h[(size_t)sB * ND + 2 * lane];
        float2 c = *(const float2*)&h[(size_t)sC * ND + 2 * lane];
        float2 d = *(const float2*)&h[(size_t)sD * ND + 2 * lane];
        acc0 += (double)a.x * eA; acc1 += (double)a.y * eA; den += (double)eA;
        acc0 += (double)b.x * eB; acc1 += (double)b.y * eB; den += (double)eB;
        acc0 += (double)c.x * eC; acc1 += (double)c.y * eC; den += (double)eC;
        acc0 += (double)d.x * eD; acc1 += (double)d.y * eD; den += (double)eD;
    }
    for (; i < s1; ++i) {
        int s = ent[i];
        float e = expv[(size_t)i * NH + hh];
        float2 a = *(const float2*)&h[(size_t)s * ND + 2 * lane];
        acc0 += (double)a.x * e; acc1 += (double)a.y * e; den += (double)e;
    }
    double inv = den > 0.0 ? 1.0 / den : 0.0;
    float2 o = make_float2((float)(acc0 * inv), (float)(acc1 * inv));
    *(float2*)&outb[(size_t)wv * ND + 2 * lane] = o;
}

// ---------- one-pass BN stats ----------
template <int M>
__global__ __launch_bounds__(256) void bn_stats1_k(const float* __restrict__ X,
                                                   double* __restrict__ stats, int rpb) {
    constexpr int G = 256 / M;
    __shared__ double sh0[256], sh1[256];
    int f = threadIdx.x % M, g = threadIdx.x / M;
    int r0 = blockIdx.x * rpb;
    int rend = r0 + rpb; if (rend > NN) rend = NN;
    double s = 0.0, s2 = 0.0;
    for (int r = r0 + g; r < rend; r += G) {
        double v = (double)X[(size_t)r * M + f];
        s += v;
        s2 += v * v;
    }
    sh0[threadIdx.x] = s;
    sh1[threadIdx.x] = s2;
    __syncthreads();
    if (g == 0) {
#pragma unroll
        for (int gg = 1; gg < G; ++gg) { s += sh0[gg * M + f]; s2 += sh1[gg * M + f]; }
        atomicAdd(&stats[f], s);
        atomicAdd(&stats[M + f], s2);
    }
}

template <int M>
__global__ void bn_fin_k(const double* __restrict__ stats,
                         const float* __restrict__ gamma, const float* __restrict__ beta,
                         float2* __restrict__ ss) {
    int f = threadIdx.x;
    if (f >= M) return;
    double mu = stats[f] / (double)NN;
    double var = stats[M + f] / (double)NN - mu * mu;
    if (var < 0.0) var = 0.0;
    double sc = (double)gamma[f] / sqrt(var + BN_EPS);
    ss[f] = make_float2((float)sc, (float)((double)beta[f] - mu * sc));
}

template <int M, int ACT>
__global__ __launch_bounds__(256) void bn_apply_ss_k(const float* __restrict__ X,
                                                     const float2* __restrict__ ss,
                                                     float* __restrict__ Y) {
    int id = blockIdx.x * 256 + threadIdx.x;
    if (id >= NN * M) return;
    float2 s = ss[id % M];
    float v = X[id] * s.x + s.y;
    if (ACT == 0) v = v > 0.0f ? v : expm1f(v);
    else          v = v > 0.0f ? v : 0.0f;
    Y[id] = v;
}

// ---------- edge logits: FLAT, 16 lanes/edge, fused pr|pc buffer (coalesced writes) ----------
__global__ __launch_bounds__(256) void edge_logits_k(const int* __restrict__ ei,
                                                     const float4* __restrict__ fused4,
                                                     const float4* __restrict__ bs14,
                                                     const float4* __restrict__ Ws24,
                                                     const float* __restrict__ bs2,
                                                     const void* __restrict__ graw,
                                                     const int* __restrict__ flags,
                                                     float* __restrict__ out) {
    int tid = blockIdx.x * 256 + threadIdx.x;
    int e = tid >> 4;
    int g = tid & 15;
    if (e >= NE) return;
    int r = ei[e], c = ei[NE + e];
    if ((unsigned)r >= NN || (unsigned)c >= NN) return;
    float4 a = fused4[(size_t)r * 32 + g];
    float4 b = fused4[(size_t)c * 32 + 16 + g];
    float4 s1 = bs14[g];
    float4 w2 = Ws24[g];
    double v = 0.0;
    double t0 = (double)a.x + (double)b.x + (double)s1.x; t0 = t0 > 0.0 ? t0 : 0.0;
    double t1 = (double)a.y + (double)b.y + (double)s1.y; t1 = t1 > 0.0 ? t1 : 0.0;
    double t2 = (double)a.z + (double)b.z + (double)s1.z; t2 = t2 > 0.0 ? t2 : 0.0;
    double t3 = (double)a.w + (double)b.w + (double)s1.w; t3 = t3 > 0.0 ? t3 : 0.0;
    v = t0 * (double)w2.x + t1 * (double)w2.y + t2 * (double)w2.z + t3 * (double)w2.w;
#pragma unroll
    for (int off = 8; off > 0; off >>= 1) v += __shfl_xor(v, off, 64);
    if (g == 0) {
        double L = v + (double)bs2[0];
        double g0, g1;
        if (flags[2]) {
            const float* gp = (const float*)graw;
            g0 = (double)gp[2 * e]; g1 = (double)gp[2 * e + 1];
        } else {
            const bf16* gp = (const bf16*)graw;
            g0 = (double)b2f(gp[2 * e]); g1 = (double)b2f(gp[2 * e + 1]);
        }
        out[WOFF + e] = ((L + g1) > g0) ? 1.0f : 0.0f;
        out[LOFF + e] = (float)L;
    }
}

// ---------- sparse agg gather: ballot-compaction + float2 packing + unroll-4 ----------
__global__ __launch_bounds__(256) void agg_gather_k(const int* __restrict__ offs,
                                                    const int* __restrict__ entc,
                                                    const int* __restrict__ ente,
                                                    const float* __restrict__ w,
                                                    const float* __restrict__ hb,
                                                    float* __restrict__ aggF) {
    __shared__ int selBuf[4][64];
    int wv = (blockIdx.x * 256 + threadIdx.x) >> 6;
    int lane = threadIdx.x & 63;
    int wloc = (threadIdx.x >> 6);
    if (wv >= NN) return;
    int* sel = selBuf[wloc];
    const int s0 = offs[wv], s1 = offs[wv + 1];
    double a0 = 0.0, a1 = 0.0;
    for (int base = s0; base < s1; base += 64) {
        int i = base + lane;
        int c = 0;
        bool keep = false;
        if (i < s1) {
            c = entc[i];
            keep = w[ente[i]] > 0.5f;
        }
        unsigned long long m = __ballot(keep);
        int cnt = __popcll(m);
        if (keep) {
            int pos = __popcll(m & ((1ULL << lane) - 1ULL));
            sel[pos] = c;
        }
        __builtin_amdgcn_wave_barrier();
        int j = 0;
        for (; j + 4 <= cnt; j += 4) {
            int cA = sel[j], cB = sel[j + 1], cC = sel[j + 2], cD = sel[j + 3];
            float2 hA = *(const float2*)&hb[(size_t)cA * ND + 2 * lane];
            float2 hB = *(const float2*)&hb[(size_t)cB * ND + 2 * lane];
            float2 hC = *(const float2*)&hb[(size_t)cC * ND + 2 * lane];
            float2 hD = *(const float2*)&hb[(size_t)cD * ND + 2 * lane];
            a0 += (double)hA.x; a1 += (double)hA.y;
            a0 += (double)hB.x; a1 += (double)hB.y;
            a0 += (double)hC.x; a1 += (double)hC.y;
            a0 += (double)hD.x; a1 += (double)hD.y;
        }
        for (; j < cnt; ++j) {
            int c2 = sel[j];
            float2 hv = *(const float2*)&hb[(size_t)c2 * ND + 2 * lane];
            a0 += (double)hv.x; a1 += (double)hv.y;
        }
        __builtin_amdgcn_wave_barrier();
    }
    float2 o = make_float2((float)a0, (float)a1);
    *(float2*)&aggF[(size_t)wv * ND + 2 * lane] = o;
}

// ---------- log-softmax (fp32) ----------
__global__ __launch_bounds__(256) void logsoftmax_k(const float* __restrict__ Y,
                                                    float* __restrict__ out) {
    int wid = (blockIdx.x * 256 + threadIdx.x) / 64;
    int lane = threadIdx.x & 63;
    if (wid >= NN) return;
    float v = (lane < NOUT) ? Y[(size_t)wid * NOUT + lane] : -1e30f;
    float m = v;
#pragma unroll
    for (int off = 32; off > 0; off >>= 1) {
        float o = __shfl_xor(m, off, 64);
        m = m > o ? m : o;
    }
    float ex = (lane < NOUT) ? expf(v - m) : 0.0f;
    float s = ex;
#pragma unroll
    for (int off = 32; off > 0; off >>= 1) s += __shfl_xor(s, off, 64);
    if (lane < NOUT) out[(size_t)wid * NOUT + lane] = v - m - logf(s);
}

extern "C" void kernel_launch(void* const* d_in, const int* in_sizes, int n_in,
                              void* d_out, int out_size, void* d_ws, size_t ws_size,
                              hipStream_t stream) {
    float* out = (float*)d_out;

    static const int EXPS[NIN] = {
        NN * 128, 2 * NE, 2 * NE, 16384, 128, 16384, 128, 128, 128, 128, 128,
        16384, 128, 128, 128, 128, 128, 16384, 64, 64, 1, 8192, 64, 64, 64, 2560, 40 };
    if (n_in != NIN) { sent_k<<<1, 1, 0, stream>>>(out, 700.0f); return; }
    if (out_size != NN * NOUT + 2 * NE) { sent_k<<<1, 1, 0, stream>>>(out, 600.0f); return; }
    for (int i = 0; i < NIN; ++i)
        if (in_sizes[i] != EXPS[i]) {
            sent_k<<<1, 1, 0, stream>>>(out, 1000.0f + 128.0f * i);
            return;
        }

    // ---- workspace layout ----
    char* W = (char*)d_ws;
    double* a_src = (double*)W;                      W += (size_t)NN * NH * 8;
    double* a_dst = (double*)W;                      W += (size_t)NN * NH * 8;
    double* stats = (double*)W;                      W += 256 * 8;
    unsigned long long* keyM = (unsigned long long*)W; W += 16 * 8;
    float2* ss = (float2*)W;                         W += 128 * 8;
    float* F1 = (float*)W;                           W += (size_t)NN * ND * 4;
    float* F2 = (float*)W;                           W += (size_t)NN * ND * 4;
    float* F3 = (float*)W;                           W += (size_t)NN * ND * 4;
    float* F4 = (float*)W;                           W += (size_t)NN * ND * 4;
    float* expv = (float*)W;                         W += (size_t)NA * NH * 4;
    float* wa = (float*)W;
    int off = 0;
    float* aW_res = wa + off; off += 16384;
    float* ab_res = wa + off; off += 128;
    float* aWg1 = wa + off; off += 16384;
    float* aas1 = wa + off; off += 128;
    float* aad1 = wa + off; off += 128;
    float* ag1  = wa + off; off += 128;
    float* abe1 = wa + off; off += 128;
    float* aWg2 = wa + off; off += 16384;
    float* aas2 = wa + off; off += 128;
    float* aad2 = wa + off; off += 128;
    float* ag2  = wa + off; off += 128;
    float* abe2 = wa + off; off += 128;
    float* aWs1 = wa + off; off += 16384;
    float* abs1 = wa + off; off += 64;
    float* aWs2 = wa + off; off += 64;
    float* abs2 = wa + off; off += 4;
    float* aWc1 = wa + off; off += 8192;
    float* abc1 = wa + off; off += 64;
    float* agc  = wa + off; off += 64;
    float* abec = wa + off; off += 64;
    float* aWc2 = wa + off; off += 2560;
    float* abc2 = wa + off; off += 40;
    float* aWs1f = wa + off; off += 16384;
    off = (off + 3) & ~3;                            // 16B-align the bf16 plane region
    ushort* wb = (ushort*)(wa + off); off += 110592; // 5 matrices x 3 bf16 planes
    W = (char*)(wa + off);
    int* ei    = (int*)W;  W += (size_t)2 * NE * 4;
    int* offsG = (int*)W;  W += (size_t)(NN + 1) * 4;
    int* curG  = (int*)W;  W += (size_t)NN * 4;
    int* entG  = (int*)W;  W += (size_t)NA * 4;
    int* entD  = (int*)W;  W += (size_t)NA * 4;
    int* offsR = (int*)W;  W += (size_t)(NN + 1) * 4;
    int* curR  = (int*)W;  W += (size_t)NN * 4;
    int* entRc = (int*)W;  W += (size_t)NE * 4;
    int* entRe = (int*)W;  W += (size_t)NE * 4;
    int* bsums = (int*)W;  W += 260 * 4;
    int* flags = (int*)W;  W += 32 * 4;
    int* errflag = (int*)W; W += 4;
    if ((size_t)(W - (char*)d_ws) > ws_size) { sent_k<<<1, 1, 0, stream>>>(out, 900.0f); return; }

    const int NB = ceil_div(NN, 256);

    // ---- 0) detect & convert ----
    Ptrs P;
    for (int i = 0; i < NIN; ++i) { P.p[i] = d_in[i]; P.n[i] = in_sizes[i]; }
    detect_k<<<NIN, 64, 0, stream>>>(P, flags);
    conv_i_k<<<ceil_div(2 * NE, 256), 256, 0, stream>>>(d_in[1], flags, ei, 2 * NE);
    conv_f_k<<<ceil_div(NN * 128, 256), 256, 0, stream>>>(d_in[0], flags, 0, F2, NN * 128);
    {
        ConvTab T;
        struct { int idx; float* dst; int n; } convs[NCV] = {
            {3, aW_res, 16384}, {4, ab_res, 128}, {5, aWg1, 16384}, {6, aas1, 128},
            {7, aad1, 128}, {9, ag1, 128}, {10, abe1, 128}, {11, aWg2, 16384},
            {12, aas2, 128}, {13, aad2, 128}, {15, ag2, 128}, {16, abe2, 128},
            {17, aWs1, 16384}, {18, abs1, 64}, {19, aWs2, 64}, {20, abs2, 1},
            {21, aWc1, 8192}, {22, abc1, 64}, {23, agc, 64}, {24, abec, 64},
            {25, aWc2, 2560}, {26, abc2, 40},
        };
        for (int i = 0; i < NCV; ++i) {
            T.src[i] = convs[i].idx;
            T.dstOff[i] = (int)(convs[i].dst - wa);
            T.n[i] = convs[i].n;
        }
        conv_all_k<<<NCV, 256, 0, stream>>>(P, T, flags, wa);
    }
    repack_ws1_k<<<ceil_div(16384, 256), 256, 0, stream>>>(aWs1, aWs1f);
    {
        SplitTab T5;
        T5.srcOff[0] = (int)(aW_res - wa); T5.n[0] = 16384; T5.dstOff[0] = 0;
        T5.srcOff[1] = (int)(aWg1 - wa);   T5.n[1] = 16384; T5.dstOff[1] = 49152;
        T5.srcOff[2] = (int)(aWg2 - wa);   T5.n[2] = 16384; T5.dstOff[2] = 98304;
        T5.srcOff[3] = (int)(aWs1f - wa);  T5.n[3] = 16384; T5.dstOff[3] = 147456;
        T5.srcOff[4] = (int)(aWc1 - wa);   T5.n[4] = 8192;  T5.dstOff[4] = 196608;
        split_w_k<<<ceil_div(73728, 256), 256, 0, stream>>>(wa, T5, wb);
    }
    hipMemsetAsync(errflag, 0, 4, stream);
    check_k<<<ceil_div(2 * NE, 256), 256, 0, stream>>>(ei, errflag);

    // ---- CSR builds ----
    hipMemsetAsync(curG, 0, (size_t)NN * 4, stream);
    deg_dst_k<<<ceil_div(NA, 256), 256, 0, stream>>>(ei, curG);
    scan1_k<<<NB, 256, 0, stream>>>(curG, offsG, bsums, NN);
    scan2_k<<<1, 256, 0, stream>>>(bsums, NB);
    scan3_k<<<ceil_div(NN + 1, 256), 256, 0, stream>>>(offsG, bsums, NN, NB);
    copy_k<<<ceil_div(NN, 256), 256, 0, stream>>>(offsG, curG, NN);
    scat_dst_k<<<ceil_div(NA, 256), 256, 0, stream>>>(ei, curG, entG, entD);

    hipMemsetAsync(curR, 0, (size_t)NN * 4, stream);
    deg_row_k<<<ceil_div(NE, 256), 256, 0, stream>>>(ei, curR);
    scan1_k<<<NB, 256, 0, stream>>>(curR, offsR, bsums, NN);
    scan2_k<<<1, 256, 0, stream>>>(bsums, NB);
    scan3_k<<<ceil_div(NN + 1, 256), 256, 0, stream>>>(offsR, bsums, NN, NB);
    copy_k<<<ceil_div(NN, 256), 256, 0, stream>>>(offsR, curR, NN);
    scat_row_k<<<ceil_div(NE, 256), 256, 0, stream>>>(ei, curR, entRc, entRe);

    const int NTIL = ceil_div(NN, 64);     // 64-row tiles, grid-strided
    const int GB = 256;                    // ~1 block/CU (W-resident LDS)
    const size_t SH128 = (size_t)3 * 128 * 136 * 2 + 128 * 8 + (size_t)2 * NH * 16 * 8;
    const size_t SH64  = (size_t)3 * 64 * 136 * 2  + 128 * 8 + (size_t)2 * NH * 16 * 8;

    // ---- 1) x_proj ----
    gemm_bf16_k<128, 128, false, 0, false><<<GB, 512, SH128, stream>>>(
        F2, nullptr, nullptr, wb + 0, ab_res, F1, NN, NTIL,
        nullptr, nullptr, nullptr, nullptr, nullptr);

    // ---- GAT layer 1 (att scores fused into GEMM epilogue) ----
    hipMemsetAsync(keyM, 0, 16 * 8, stream);
    gemm_bf16_k<128, 128, false, 0, true><<<GB, 512, SH128, stream>>>(
        F1, nullptr, nullptr, wb + 49152, nullptr, F2, NN, NTIL,
        aas1, aad1, a_src, a_dst, keyM);
    edge_exp_k<<<ceil_div(NA * NH, 256), 256, 0, stream>>>(entG, entD, a_src, a_dst, keyM, expv);
    gat_gather_k<<<ceil_div(NN * 64, 256), 256, 0, stream>>>(offsG, entG, F2, expv, F4);
    hipMemsetAsync(stats, 0, 2 * ND * 8, stream);
    bn_stats1_k<128><<<ceil_div(NN, 256), 256, 0, stream>>>(F4, stats, 256);
    bn_fin_k<128><<<1, 128, 0, stream>>>(stats, ag1, abe1, ss);

    // ---- GAT layer 2 (BN1+ELU fused into X staging; att fused in epilogue) ----
    hipMemsetAsync(keyM, 0, 16 * 8, stream);
    gemm_bf16_k<128, 128, false, 1, true><<<GB, 512, SH128, stream>>>(
        F4, nullptr, ss, wb + 98304, nullptr, F2, NN, NTIL,
        aas2, aad2, a_src, a_dst, keyM);
    edge_exp_k<<<ceil_div(NA * NH, 256), 256, 0, stream>>>(entG, entD, a_src, a_dst, keyM, expv);
    gat_gather_k<<<ceil_div(NN * 64, 256), 256, 0, stream>>>(offsG, entG, F2, expv, F4);
    hipMemsetAsync(stats, 0, 2 * ND * 8, stream);
    bn_stats1_k<128><<<ceil_div(NN, 256), 256, 0, stream>>>(F4, stats, 256);
    bn_fin_k<128><<<1, 128, 0, stream>>>(stats, ag2, abe2, ss);
    bn_apply_ss_k<128, 0><<<ceil_div(NN * ND, 256), 256, 0, stream>>>(F4, ss, F3);  // h_base

    // ---- fused pr|pc gemm ----
    gemm_bf16_k<128, 128, false, 0, false><<<GB, 512, SH128, stream>>>(
        F3, nullptr, nullptr, wb + 147456, nullptr, F2, NN, NTIL,
        nullptr, nullptr, nullptr, nullptr, nullptr);

    // ---- edge logits (flat: coalesced writes) ----
    edge_logits_k<<<ceil_div(NE * 16, 256), 256, 0, stream>>>(
        ei, (const float4*)F2, (const float4*)abs1, (const float4*)aWs2, abs2, d_in[2], flags,
        out);

    // ---- agg (ballot-compacted gather) -> F1 ----
    agg_gather_k<<<ceil_div(NN * 64, 256), 256, 0, stream>>>(offsR, entRc, entRe, out + WOFF,
                                                             F3, F1);

    // ---- t = (h_base + agg) @ Wc1.T + bc1 ----
    gemm_bf16_k<64, 128, true, 0, false><<<GB, 512, SH64, stream>>>(
        F3, F1, nullptr, wb + 196608, abc1, F4, NN, NTIL,
        nullptr, nullptr, nullptr, nullptr, nullptr);

    hipMemsetAsync(stats, 0, 2 * NHID * 8, stream);
    bn_stats1_k<64><<<ceil_div(NN, 256), 256, 0, stream>>>(F4, stats, 256);
    bn_fin_k<64><<<1, 64, 0, stream>>>(stats, agc, abec, ss);

    // ---- logits (BN+ReLU fused into X staging) ----
    float* logits = F4 + (size_t)NN * NHID;
    gemm_k<40, 64, 10, false, 2, false><<<ceil_div(NN, 100), 256, 0, stream>>>(
        F4, nullptr, ss, aWc2, 64, abc2, logits, NN,
        nullptr, nullptr, nullptr, nullptr, nullptr);

    logsoftmax_k<<<ceil_div(NN * 64, 256), 256, 0, stream>>>(logits, out);

    finalize_k<<<1, 1, 0, stream>>>(errflag, out);
}

// Round 5
// 989.830 us; speedup vs baseline: 1.0727x; 1.0727x over previous
//
#include <hip/hip_runtime.h>
#include <hip/hip_bf16.h>

#define NN 50000
#define NE 800000
#define NA (NE + NN)
#define NH 8
#define NC 16
#define ND 128
#define NHID 64
#define NSH 64
#define NOUT 40
#define BN_EPS 1e-5

#define WOFF (NN * NOUT)
#define LOFF (WOFF + NE)
#define NIN 27
#define NCV 22

static inline int ceil_div(int a, int b) { return (a + b - 1) / b; }

typedef __hip_bfloat16 bf16;
__device__ inline float b2f(bf16 v) { return __bfloat162float(v); }

typedef short bf16x8v __attribute__((ext_vector_type(8)));
typedef float f32x4v __attribute__((ext_vector_type(4)));

struct Ptrs { const void* p[NIN]; int n[NIN]; };
struct ConvTab { int src[NCV]; int dstOff[NCV]; int n[NCV]; };
struct SplitTab { int srcOff[5]; int dstOff[5]; int n[5]; };

__global__ void sent_k(float* out, float v) { out[0] = v; }

// exact 3-way bf16 split via RNE (used once for weights): v = b0+b1+b2 exactly
__device__ inline void split3(float v, ushort* o0, ushort* o1, ushort* o2) {
    bf16 h0 = __float2bfloat16(v);
    float r1 = v - __bfloat162float(h0);
    bf16 h1 = __float2bfloat16(r1);
    float r2 = r1 - __bfloat162float(h1);
    bf16 h2 = __float2bfloat16(r2);
    __builtin_memcpy(o0, &h0, 2);
    __builtin_memcpy(o1, &h1, 2);
    __builtin_memcpy(o2, &h2, 2);
}
__device__ inline short f2bs(float v) {
    bf16 h = __float2bfloat16(v);
    short s;
    __builtin_memcpy(&s, &h, 2);
    return s;
}

// ---------- dtype detection (fp32 vs bf16; int32 vs int64) ----------
__global__ __launch_bounds__(64) void detect_k(Ptrs P, int* flags) {
    int b = blockIdx.x, lane = threadIdx.x;
    const void* p = P.p[b];
    int n = P.n[b];
    if (b == 1) {
        const int* w = (const int*)p;
        int m = n < 256 ? n : 256;
        int oddNz = 0;
        for (int i = lane; i < m; i += 64)
            if ((i & 1) && w[i] != 0) oddNz = 1;
        unsigned long long any = __ballot(oddNz);
        if (lane == 0) flags[1] = (any == 0ULL) ? 1 : 0;   // 1 => int64
        return;
    }
    int m = n < 256 ? n : 256;
    const bf16* hb = (const bf16*)p;
    int impl = 0, evenNz = 0, oddNz = 0;
    for (int i = lane; i < m; i += 64) {
        float v = b2f(hb[i]);
        bool bad = !isfinite(v) || fabsf(v) > 64.0f || (v != 0.0f && fabsf(v) < 1e-6f);
        if (bad) impl++;
        if (v != 0.0f) { if (i & 1) oddNz = 1; else evenNz = 1; }
    }
#pragma unroll
    for (int off = 32; off > 0; off >>= 1) impl += __shfl_down(impl, off, 64);
    unsigned long long be = __ballot(evenNz), bo = __ballot(oddNz);
    if (lane == 0) {
        int thresh = (m >= 8) ? (m / 8) : 1;
        int isF32 = 0;
        if (impl >= thresh) isF32 = 1;
        else if (be == 0ULL && bo != 0ULL) isF32 = 1;
        flags[b] = isF32;
    }
}

__global__ __launch_bounds__(256) void conv_f_k(const void* __restrict__ src,
                                                const int* __restrict__ flags, int fi,
                                                float* __restrict__ dst, int n) {
    int i = blockIdx.x * 256 + threadIdx.x;
    if (i >= n) return;
    dst[i] = flags[fi] ? ((const float*)src)[i] : b2f(((const bf16*)src)[i]);
}

__global__ __launch_bounds__(256) void conv_all_k(Ptrs P, ConvTab T,
                                                  const int* __restrict__ flags,
                                                  float* __restrict__ wa) {
    int b = blockIdx.x;
    const void* src = P.p[T.src[b]];
    int isf = flags[T.src[b]];
    float* dst = wa + T.dstOff[b];
    int n = T.n[b];
    for (int i = threadIdx.x; i < n; i += 256)
        dst[i] = isf ? ((const float*)src)[i] : b2f(((const bf16*)src)[i]);
}

// repack Ws1 [64][256] -> fused [128][128]
__global__ __launch_bounds__(256) void repack_ws1_k(const float* __restrict__ s,
                                                    float* __restrict__ d) {
    int id = blockIdx.x * 256 + threadIdx.x;
    if (id >= 128 * 128) return;
    int m = id >> 7, k = id & 127;
    d[id] = (m < 64) ? s[m * 256 + k] : s[(m - 64) * 256 + 128 + k];
}

// split the 5 MFMA weight matrices into 3 bf16 planes each
__global__ __launch_bounds__(256) void split_w_k(const float* __restrict__ wa,
                                                 SplitTab T, ushort* __restrict__ wb) {
    int id = blockIdx.x * 256 + threadIdx.x;
    for (int m = 0; m < 5; ++m) {
        if (id < T.n[m]) {
            float v = wa[T.srcOff[m] + id];
            ushort b0, b1, b2;
            split3(v, &b0, &b1, &b2);
            ushort* d = wb + T.dstOff[m];
            d[id] = b0;
            d[T.n[m] + id] = b1;
            d[2 * T.n[m] + id] = b2;
            return;
        }
        id -= T.n[m];
    }
}

__global__ __launch_bounds__(256) void conv_i_k(const void* __restrict__ src,
                                                const int* __restrict__ flags,
                                                int* __restrict__ dst, int n) {
    int i = blockIdx.x * 256 + threadIdx.x;
    if (i >= n) return;
    const int* s = (const int*)src;
    dst[i] = flags[1] ? s[2 * i] : s[i];
}

__global__ __launch_bounds__(256) void check_k(const int* __restrict__ ei, int* err) {
    int i = blockIdx.x * 256 + threadIdx.x;
    if (i < 2 * NE && (unsigned)ei[i] >= NN) atomicOr(err, 1);
}
__global__ void finalize_k(const int* err, float* out) {
    if (*err) out[0] = 800.0f;
}

// ---------- ordered-key mapping for fp64 atomic max ----------
__device__ inline unsigned long long d2key(double v) {
    unsigned long long b = __double_as_longlong(v);
    return (b & 0x8000000000000000ULL) ? ~b : (b | 0x8000000000000000ULL);
}
__device__ inline double key2d(unsigned long long k) {
    return (k & 0x8000000000000000ULL) ? __longlong_as_double(k & 0x7fffffffffffffffULL)
                                       : __longlong_as_double(~k);
}

// ---------- CSR build ----------
__global__ __launch_bounds__(256) void deg_dst_k(const int* __restrict__ ei, int* deg) {
    int e = blockIdx.x * 256 + threadIdx.x;
    if (e >= NA) return;
    int d = (e < NE) ? ei[NE + e] : e - NE;
    if ((unsigned)d < NN) atomicAdd(&deg[d], 1);
}
__global__ __launch_bounds__(256) void deg_row_k(const int* __restrict__ ei, int* deg) {
    int e = blockIdx.x * 256 + threadIdx.x;
    if (e >= NE) return;
    int r = ei[e];
    if ((unsigned)r < NN) atomicAdd(&deg[r], 1);
}

__global__ __launch_bounds__(256) void scan1_k(const int* __restrict__ deg,
                                               int* __restrict__ offs,
                                               int* __restrict__ bsums, int n) {
    __shared__ int sh[256];
    int i = blockIdx.x * 256 + threadIdx.x;
    int v = (i < n) ? deg[i] : 0;
    sh[threadIdx.x] = v;
    __syncthreads();
    int acc = v;
    for (int off = 1; off < 256; off <<= 1) {
        int t = (threadIdx.x >= off) ? sh[threadIdx.x - off] : 0;
        __syncthreads();
        acc += t;
        sh[threadIdx.x] = acc;
        __syncthreads();
    }
    if (i < n) offs[i] = acc - v;
    if (threadIdx.x == 255) bsums[blockIdx.x] = acc;
}
__global__ __launch_bounds__(256) void scan2_k(int* __restrict__ bsums, int nb) {
    __shared__ int sh[256];
    int t = threadIdx.x;
    int v = (t < nb) ? bsums[t] : 0;
    sh[t] = v;
    __syncthreads();
    int acc = v;
    for (int off = 1; off < 256; off <<= 1) {
        int x = (t >= off) ? sh[t - off] : 0;
        __syncthreads();
        acc += x;
        sh[t] = acc;
        __syncthreads();
    }
    if (t < nb) bsums[t] = acc - v;
    if (t == nb - 1) bsums[nb] = acc;
}
__global__ __launch_bounds__(256) void scan3_k(int* __restrict__ offs,
                                               const int* __restrict__ bsums, int n, int nb) {
    int i = blockIdx.x * 256 + threadIdx.x;
    if (i < n) offs[i] += bsums[blockIdx.x];
    else if (i == n) offs[n] = bsums[nb];
}
__global__ __launch_bounds__(256) void copy_k(const int* __restrict__ a, int* __restrict__ b,
                                              int n) {
    int i = blockIdx.x * 256 + threadIdx.x;
    if (i < n) b[i] = a[i];
}

__global__ __launch_bounds__(256) void scat_dst_k(const int* __restrict__ ei, int* cur,
                                                  int* __restrict__ entS,
                                                  int* __restrict__ entD) {
    int e = blockIdx.x * 256 + threadIdx.x;
    if (e >= NA) return;
    int s, d;
    if (e < NE) { s = ei[e]; d = ei[NE + e]; }
    else        { s = d = e - NE; }
    if ((unsigned)s >= NN || (unsigned)d >= NN) return;
    int pos = atomicAdd(&cur[d], 1);
    entS[pos] = s;
    entD[pos] = d;
}
__global__ __launch_bounds__(256) void scat_row_k(const int* __restrict__ ei, int* cur,
                                                  int* __restrict__ entc,
                                                  int* __restrict__ ente) {
    int e = blockIdx.x * 256 + threadIdx.x;
    if (e >= NE) return;
    int r = ei[e], c = ei[NE + e];
    if ((unsigned)r >= NN || (unsigned)c >= NN) return;
    int pos = atomicAdd(&cur[r], 1);
    entc[pos] = c;
    ente[pos] = e;
}

// ---------- bf16x3-split MFMA GEMM, col-split W-resident LDS, X in registers ----------
// Y[nrows x M] = X[nrows x K] @ W[M x K]^T, K=128.
// Each block owns MB=64 output cols (colblk = blockIdx % (M/MB)) -> LDS ~53 KB
// -> 2 blocks/CU resident = 4 waves/SIMD, matching the 128-VGPR codegen of
// __launch_bounds__(512,2) (round-4 lesson: LDS 104 KB left only 2 waves/SIMD).
// 8 waves = 4 row-groups x 2 col-groups; wave = 16 rows x 32 cols (TW=2).
// X loaded per-lane from global (coalesced 16x128B), transformed, and split
// v = b0+b1+b2 via EXACT truncation bit-ops (~8 VALU/elem vs ~28 for RNE):
//   b0 = bits&0xffff0000; r1 = v-b0 (exact); b1 = bits(r1)&...; r2 exact; b2 = r2.
// Numerics class unchanged: hi=mfma(a0,w0) flushed to f64 per 32-K chunk (~1e-7),
// lo-chain a0w1,a1w0,a0w2,a1w1,a2w0 in fp32 (2^-8-scaled). C/D layout PROBED at
// runtime (self-consistent under lane relabeling).
template <int M, int MB, bool ADD2, int XBN, bool ATT>
__global__ __launch_bounds__(512, 2) void gemm_bf16_k(const float* __restrict__ X,
                                                      const float* __restrict__ X2,
                                                      const float2* __restrict__ ssX,
                                                      const ushort* __restrict__ Wb,
                                                      const float* __restrict__ bias,
                                                      float* __restrict__ Y, int nrows,
                                                      int ntiles,
                                                      const float* __restrict__ asw,
                                                      const float* __restrict__ adw,
                                                      double* __restrict__ a_src,
                                                      double* __restrict__ a_dst,
                                                      unsigned long long* __restrict__ keyM) {
    constexpr int K = 128;
    constexpr int NCB = M / MB;           // column-blocks
    constexpr int TW = MB / 32;           // 16x16 tiles per wave (=2)
    constexpr int LP = K + 8;             // padded LDS row (bf16 elems), 272B
    constexpr int SZW = 3 * MB * LP * 2;  // W planes bytes
    static_assert(!ATT || M == 128, "ATT epilogue requires M==128");

    extern __shared__ char smem[];
    ushort* Wsm = (ushort*)smem;
    float2* ssS = (float2*)(smem + SZW);
    double* redS = (double*)(smem + SZW + K * 8);   // [4][16]
    double* redD = redS + 4 * 16;

    const int t = threadIdx.x;
    const int l = t & 63, wv = t >> 6;
    const int rg = wv & 3;                // row group (16 rows)
    const int cg = wv >> 2;               // col group (0..1)
    const int lr = l & 15;
    const int lk = l >> 4;
    const int colblk = blockIdx.x % NCB;
    const int colL = cg * (MB / 2);       // local col base within block (0 or 32)
    const int colbase = colblk * MB + colL;

    // ---- stage this block's W column-slice (3 planes) once ----
    for (int p = 0; p < 3; ++p)
        for (int idx = t; idx < MB * K / 8; idx += 512) {
            int m = idx >> 4;             // local row; K/8=16 octets per row
            int ko = (idx & 15) * 8;
            *(uint4*)&Wsm[((size_t)p * MB + m) * LP + ko] =
                *(const uint4*)&Wb[(size_t)p * (M * K) + (size_t)(colblk * MB + m) * K + ko];
        }
    if constexpr (XBN != 0) {
        for (int i = t; i < K; i += 512) ssS[i] = ssX[i];
    }
    __syncthreads();

    const f32x4v zz = {0.0f, 0.0f, 0.0f, 0.0f};

    // ---- runtime C/D layout probe (2 MFMAs) ----
    int rowD[4], colD[4];
    {
        bf16x8v pLr = {0, 0, 0, 0, 0, 0, 0, 0};
        bf16x8v pOne = pLr;
        if (lk == 0) {
            pLr[0] = f2bs((float)lr);
            pOne[0] = f2bs(1.0f);
        }
        f32x4v dr = __builtin_amdgcn_mfma_f32_16x16x32_bf16(pLr, pOne, zz, 0, 0, 0);
        f32x4v dc = __builtin_amdgcn_mfma_f32_16x16x32_bf16(pOne, pLr, zz, 0, 0, 0);
#pragma unroll
        for (int r = 0; r < 4; ++r) {
            rowD[r] = (int)dr[r];
            colD[r] = (int)dc[r];
        }
    }

    for (int tile = blockIdx.x / NCB; tile < ntiles; tile += gridDim.x / NCB) {
        const int row0 = tile * 64;
        const int xrow = row0 + rg * 16 + lr;
        const bool rowok = xrow < nrows;
        const float* xp = X + (size_t)xrow * K;

        f32x4v hi[TW], lo[TW];
        double acc[TW][4];
#pragma unroll
        for (int tt = 0; tt < TW; ++tt) {
            hi[tt] = zz;
            lo[tt] = zz;
#pragma unroll
            for (int i = 0; i < 4; ++i) acc[tt][i] = 0.0;
        }

#pragma unroll
        for (int kc = 0; kc < K / 32; ++kc) {
            const int kb = kc * 32 + lk * 8;
            float xv[8];
#pragma unroll
            for (int j = 0; j < 8; ++j) xv[j] = 0.0f;
            if (rowok) {
                float4 va = *(const float4*)(xp + kb);
                float4 vb = *(const float4*)(xp + kb + 4);
                xv[0] = va.x; xv[1] = va.y; xv[2] = va.z; xv[3] = va.w;
                xv[4] = vb.x; xv[5] = vb.y; xv[6] = vb.z; xv[7] = vb.w;
                if constexpr (ADD2) {
                    const float* xp2 = X2 + (size_t)xrow * K;
                    float4 wa2 = *(const float4*)(xp2 + kb);
                    float4 wb2 = *(const float4*)(xp2 + kb + 4);
                    xv[0] += wa2.x; xv[1] += wa2.y; xv[2] += wa2.z; xv[3] += wa2.w;
                    xv[4] += wb2.x; xv[5] += wb2.y; xv[6] += wb2.z; xv[7] += wb2.w;
                }
                if constexpr (XBN != 0) {
#pragma unroll
                    for (int j = 0; j < 8; ++j) {
                        float2 s = ssS[kb + j];
                        float v = xv[j] * s.x + s.y;
                        xv[j] = (XBN == 1) ? (v > 0.0f ? v : expm1f(v))
                                           : (v > 0.0f ? v : 0.0f);
                    }
                }
            }
            // exact truncation split: v = b0 + b1 + b2 (pure bit ops)
            bf16x8v A0, A1, A2;
#pragma unroll
            for (int j = 0; j < 8; ++j) {
                unsigned u0 = __float_as_uint(xv[j]);
                float f0 = __uint_as_float(u0 & 0xffff0000u);
                float r1 = xv[j] - f0;
                unsigned u1 = __float_as_uint(r1);
                float f1 = __uint_as_float(u1 & 0xffff0000u);
                float r2 = r1 - f1;
                unsigned u2 = __float_as_uint(r2);
                A0[j] = (short)(u0 >> 16);
                A1[j] = (short)(u1 >> 16);
                A2[j] = (short)(u2 >> 16);
            }

#pragma unroll
            for (int tt = 0; tt < TW; ++tt) {
                const int bc = colL + tt * 16 + lr;    // local W row
                bf16x8v B0 = *(const bf16x8v*)&Wsm[((size_t)0 * MB + bc) * LP + kb];
                bf16x8v B1 = *(const bf16x8v*)&Wsm[((size_t)1 * MB + bc) * LP + kb];
                bf16x8v B2 = *(const bf16x8v*)&Wsm[((size_t)2 * MB + bc) * LP + kb];
                hi[tt] = __builtin_amdgcn_mfma_f32_16x16x32_bf16(A0, B0, hi[tt], 0, 0, 0);
                lo[tt] = __builtin_amdgcn_mfma_f32_16x16x32_bf16(A0, B1, lo[tt], 0, 0, 0);
                lo[tt] = __builtin_amdgcn_mfma_f32_16x16x32_bf16(A1, B0, lo[tt], 0, 0, 0);
                lo[tt] = __builtin_amdgcn_mfma_f32_16x16x32_bf16(A0, B2, lo[tt], 0, 0, 0);
                lo[tt] = __builtin_amdgcn_mfma_f32_16x16x32_bf16(A1, B1, lo[tt], 0, 0, 0);
                lo[tt] = __builtin_amdgcn_mfma_f32_16x16x32_bf16(A2, B0, lo[tt], 0, 0, 0);
            }
            // flush hi-acc to f64 per K-chunk
#pragma unroll
            for (int tt = 0; tt < TW; ++tt) {
#pragma unroll
                for (int i = 0; i < 4; ++i) acc[tt][i] += (double)hi[tt][i];
                hi[tt] = zz;
            }
        }

        // epilogue: add lo, bias, fp32 round, store (probed row/col)
        int rowg[4];
#pragma unroll
        for (int i = 0; i < 4; ++i) rowg[i] = row0 + rg * 16 + rowD[i];

        float yv[TW][4];
#pragma unroll
        for (int tt = 0; tt < TW; ++tt) {
#pragma unroll
            for (int i = 0; i < 4; ++i) {
                int col = colbase + tt * 16 + colD[i];
                double v = acc[tt][i] + (double)lo[tt][i];
                if (bias) v += (double)bias[col];
                yv[tt][i] = (float)v;
                if (rowg[i] < nrows) Y[(size_t)rowg[i] * M + col] = yv[tt][i];
            }
        }

        if constexpr (ATT) {
            // 16-col tile == one head; block covers heads colblk*4 .. +3
#pragma unroll
            for (int tt = 0; tt < TW; ++tt) {
                const int hl = cg * 2 + tt;            // head-local 0..3
                const int head = colblk * 4 + hl;
                double s[4], d[4];
#pragma unroll
                for (int i = 0; i < 4; ++i) {
                    int col = colbase + tt * 16 + colD[i];
                    s[i] = (double)yv[tt][i] * (double)asw[col];
                    d[i] = (double)yv[tt][i] * (double)adw[col];
                }
#pragma unroll
                for (int off = 1; off <= 8; off <<= 1) {
#pragma unroll
                    for (int i = 0; i < 4; ++i) {
                        s[i] += __shfl_xor(s[i], off, 64);
                        d[i] += __shfl_xor(d[i], off, 64);
                    }
                }
                if (lr == 0) {
                    double mS = -1e300, mD = -1e300;
#pragma unroll
                    for (int i = 0; i < 4; ++i) {
                        if (rowg[i] < nrows) {
                            a_src[(size_t)rowg[i] * NH + head] = s[i];
                            a_dst[(size_t)rowg[i] * NH + head] = d[i];
                            if (s[i] > mS) mS = s[i];
                            if (d[i] > mD) mD = d[i];
                        }
                    }
                    redS[hl * 16 + rg * 4 + lk] = mS;
                    redD[hl * 16 + rg * 4 + lk] = mD;
                }
            }
            __syncthreads();
            if (t < 4) {
                double mS = -1e300, mD = -1e300;
#pragma unroll
                for (int g = 0; g < 16; ++g) {
                    if (redS[t * 16 + g] > mS) mS = redS[t * 16 + g];
                    if (redD[t * 16 + g] > mD) mD = redD[t * 16 + g];
                }
                atomicMax(&keyM[colblk * 4 + t], d2key(mS));
                atomicMax(&keyM[NH + colblk * 4 + t], d2key(mD));
            }
            __syncthreads();
        }
    }
}

// ---------- legacy VALU GEMM (kept for the 40-col classifier head) ----------
template <int M, int K, int TC, bool ADD2, int XBN, bool ATT>
__global__ __launch_bounds__(256) void gemm_k(const float* __restrict__ X,
                                              const float* __restrict__ X2,
                                              const float2* __restrict__ ssX,
                                              const float* __restrict__ W, int wstride,
                                              const float* __restrict__ bias,
                                              float* __restrict__ Y, int nrows,
                                              const float* __restrict__ asw,
                                              const float* __restrict__ adw,
                                              double* __restrict__ a_src,
                                              double* __restrict__ a_dst,
                                              unsigned long long* __restrict__ keyM) {
    static_assert(!ATT || TC == 32, "ATT epilogue requires TC==32");
    constexpr int KT = 32;
    constexpr int TR = 256 / TC;
    constexpr int ROWS = TR * 4;          // multiple of 4 -> (ROWS+4)*4B is 16B-aligned
    __shared__ float Ws[KT][M + 4];
    __shared__ float Xs[KT][ROWS + 4];    // transposed tile

    const int t = threadIdx.x;
    const int lane = t & 63, wv = t >> 6;
    const int row0 = blockIdx.x * ROWS;

    double acc[4][4];
#pragma unroll
    for (int i = 0; i < 4; ++i)
#pragma unroll
        for (int j = 0; j < 4; ++j) acc[i][j] = 0.0;

    for (int k0 = 0; k0 < K; k0 += KT) {
        {
            const int mi = lane >> 3, ki = lane & 7;
            for (int b = wv; b < (M / 8) * (KT / 8); b += 4) {
                int bm = b % (M / 8), bk = b / (M / 8);
                int m = bm * 8 + mi, kk = bk * 8 + ki;
                Ws[kk][m] = W[(size_t)m * wstride + k0 + kk];
            }
        }
        for (int idx = t; idx < ROWS * KT; idx += 256) {
            int r = idx / KT, kk = idx % KT;
            int row = row0 + r;
            float v = 0.0f;
            if (row < nrows) {
                v = X[(size_t)row * K + k0 + kk];
                if (ADD2) v += X2[(size_t)row * K + k0 + kk];
                if (XBN) {
                    float2 s = ssX[k0 + kk];
                    v = v * s.x + s.y;
                    if (XBN == 1) v = v > 0.0f ? v : expm1f(v);
                    else          v = v > 0.0f ? v : 0.0f;
                }
            }
            Xs[kk][r] = v;
        }
        __syncthreads();

        if (t < TR * TC) {
            const int c0 = (t % TC) * 4;
            const int r0 = (t / TC) * 4;
            float facc[4][4];
#pragma unroll
            for (int i = 0; i < 4; ++i)
#pragma unroll
                for (int j = 0; j < 4; ++j) facc[i][j] = 0.0f;
#pragma unroll 4
            for (int kk = 0; kk < KT; ++kk) {
                float4 w = *(const float4*)&Ws[kk][c0];
                float4 x4 = *(const float4*)&Xs[kk][r0];
                float xv[4] = {x4.x, x4.y, x4.z, x4.w};
#pragma unroll
                for (int i = 0; i < 4; ++i) {
                    facc[i][0] += xv[i] * w.x;
                    facc[i][1] += xv[i] * w.y;
                    facc[i][2] += xv[i] * w.z;
                    facc[i][3] += xv[i] * w.w;
                }
                if ((kk & 15) == 15) {
#pragma unroll
                    for (int i = 0; i < 4; ++i)
#pragma unroll
                        for (int j = 0; j < 4; ++j) {
                            acc[i][j] += (double)facc[i][j];
                            facc[i][j] = 0.0f;
                        }
                }
            }
        }
        __syncthreads();
    }

    if (t < TR * TC) {
        const int c0 = (t % TC) * 4;
        const int r0 = (t / TC) * 4;
#pragma unroll
        for (int i = 0; i < 4; ++i) {
            int row = row0 + r0 + i;
#pragma unroll
            for (int j = 0; j < 4; ++j) {
                double v = acc[i][j];
                if (bias) v += (double)bias[c0 + j];
                if (row < nrows) Y[(size_t)row * M + c0 + j] = (float)v;
            }
        }
    }
}

// ---------- edge-parallel exp (fp32 expf; x computed fp64) ----------
__global__ __launch_bounds__(256) void edge_exp_k(const int* __restrict__ entS,
                                                  const int* __restrict__ entD,
                                                  const double* __restrict__ a_src,
                                                  const double* __restrict__ a_dst,
                                                  const unsigned long long* __restrict__ keyM,
                                                  float* __restrict__ expv) {
    int id = blockIdx.x * 256 + threadIdx.x;
    if (id >= NA * NH) return;
    int i = id >> 3, hh = id & 7;
    int s = entS[i], d = entD[i];
    double x = a_src[(size_t)s * NH + hh] + a_dst[(size_t)d * NH + hh];
    x = x > 0.0 ? x : 0.2 * x;
    double M = key2d(keyM[hh]) + key2d(keyM[NH + hh]);
    if (M < 0.0) M = 0.0;
    expv[id] = expf((float)(x - M));
}

// ---------- GAT gather: wave per dst, float2 feature packing, unroll-4 ----------
__global__ __launch_bounds__(256) void gat_gather_k(const int* __restrict__ offs,
                                                    const int* __restrict__ ent,
                                                    const float* __restrict__ h,
                                                    const float* __restrict__ expv,
                                                    float* __restrict__ outb) {
    int wv = (blockIdx.x * 256 + threadIdx.x) >> 6;
    int lane = threadIdx.x & 63;
    if (wv >= NN) return;
    const int s0 = offs[wv], s1 = offs[wv + 1];
    const int hh = lane >> 3;
    double acc0 = 0.0, acc1 = 0.0, den = 0.0;
    int i = s0;
    for (; i + 4 <= s1; i += 4) {
        int sA = ent[i], sB = ent[i + 1], sC = ent[i + 2], sD = ent[i + 3];
        float eA = expv[(size_t)(i + 0) * NH + hh];
        float eB = expv[(size_t)(i + 1) * NH + hh];
        float eC = expv[(size_t)(i + 2) * NH + hh];
        float eD = expv[(size_t)(i + 3) * NH + hh];
        float2 a = *(const float2*)&h[(size_t)sA * ND + 2 * lane];
        float2 b = *(const float2*)&h[(size_t)sB * ND + 2 * lane];
        float2 c = *(const float2*)&h[(size_t)sC * ND + 2 * lane];
        float2 d = *(const float2*)&h[(size_t)sD * ND + 2 * lane];
        acc0 += (double)a.x * eA; acc1 += (double)a.y * eA; den += (double)eA;
        acc0 += (double)b.x * eB; acc1 += (double)b.y * eB; den += (double)eB;
        acc0 += (double)c.x * eC; acc1 += (double)c.y * eC; den += (double)eC;
        acc0 += (double)d.x * eD; acc1 += (double)d.y * eD; den += (double)eD;
    }
    for (; i < s1; ++i) {
        int s = ent[i];
        float e = expv[(size_t)i * NH + hh];
        float2 a = *(const float2*)&h[(size_t)s * ND + 2 * lane];
        acc0 += (double)a.x * e; acc1 += (double)a.y * e; den += (double)e;
    }
    double inv = den > 0.0 ? 1.0 / den : 0.0;
    float2 o = make_float2((float)(acc0 * inv), (float)(acc1 * inv));
    *(float2*)&outb[(size_t)wv * ND + 2 * lane] = o;
}

// ---------- one-pass BN stats ----------
template <int M>
__global__ __launch_bounds__(256) void bn_stats1_k(const float* __restrict__ X,
                                                   double* __restrict__ stats, int rpb) {
    constexpr int G = 256 / M;
    __shared__ double sh0[256], sh1[256];
    int f = threadIdx.x % M, g = threadIdx.x / M;
    int r0 = blockIdx.x * rpb;
    int rend = r0 + rpb; if (rend > NN) rend = NN;
    double s = 0.0, s2 = 0.0;
    for (int r = r0 + g; r < rend; r += G) {
        double v = (double)X[(size_t)r * M + f];
        s += v;
        s2 += v * v;
    }
    sh0[threadIdx.x] = s;
    sh1[threadIdx.x] = s2;
    __syncthreads();
    if (g == 0) {
#pragma unroll
        for (int gg = 1; gg < G; ++gg) { s += sh0[gg * M + f]; s2 += sh1[gg * M + f]; }
        atomicAdd(&stats[f], s);
        atomicAdd(&stats[M + f], s2);
    }
}

template <int M>
__global__ void bn_fin_k(const double* __restrict__ stats,
                         const float* __restrict__ gamma, const float* __restrict__ beta,
                         float2* __restrict__ ss) {
    int f = threadIdx.x;
    if (f >= M) return;
    double mu = stats[f] / (double)NN;
    double var = stats[M + f] / (double)NN - mu * mu;
    if (var < 0.0) var = 0.0;
    double sc = (double)gamma[f] / sqrt(var + BN_EPS);
    ss[f] = make_float2((float)sc, (float)((double)beta[f] - mu * sc));
}

template <int M, int ACT>
__global__ __launch_bounds__(256) void bn_apply_ss_k(const float* __restrict__ X,
                                                     const float2* __restrict__ ss,
                                                     float* __restrict__ Y) {
    int id = blockIdx.x * 256 + threadIdx.x;
    if (id >= NN * M) return;
    float2 s = ss[id % M];
    float v = X[id] * s.x + s.y;
    if (ACT == 0) v = v > 0.0f ? v : expm1f(v);
    else          v = v > 0.0f ? v : 0.0f;
    Y[id] = v;
}

// ---------- edge logits: FLAT, 16 lanes/edge, fused pr|pc buffer (coalesced writes) ----------
__global__ __launch_bounds__(256) void edge_logits_k(const int* __restrict__ ei,
                                                     const float4* __restrict__ fused4,
                                                     const float4* __restrict__ bs14,
                                                     const float4* __restrict__ Ws24,
                                                     const float* __restrict__ bs2,
                                                     const void* __restrict__ graw,
                                                     const int* __restrict__ flags,
                                                     float* __restrict__ out) {
    int tid = blockIdx.x * 256 + threadIdx.x;
    int e = tid >> 4;
    int g = tid & 15;
    if (e >= NE) return;
    int r = ei[e], c = ei[NE + e];
    if ((unsigned)r >= NN || (unsigned)c >= NN) return;
    float4 a = fused4[(size_t)r * 32 + g];
    float4 b = fused4[(size_t)c * 32 + 16 + g];
    float4 s1 = bs14[g];
    float4 w2 = Ws24[g];
    double v = 0.0;
    double t0 = (double)a.x + (double)b.x + (double)s1.x; t0 = t0 > 0.0 ? t0 : 0.0;
    double t1 = (double)a.y + (double)b.y + (double)s1.y; t1 = t1 > 0.0 ? t1 : 0.0;
    double t2 = (double)a.z + (double)b.z + (double)s1.z; t2 = t2 > 0.0 ? t2 : 0.0;
    double t3 = (double)a.w + (double)b.w + (double)s1.w; t3 = t3 > 0.0 ? t3 : 0.0;
    v = t0 * (double)w2.x + t1 * (double)w2.y + t2 * (double)w2.z + t3 * (double)w2.w;
#pragma unroll
    for (int off = 8; off > 0; off >>= 1) v += __shfl_xor(v, off, 64);
    if (g == 0) {
        double L = v + (double)bs2[0];
        double g0, g1;
        if (flags[2]) {
            const float* gp = (const float*)graw;
            g0 = (double)gp[2 * e]; g1 = (double)gp[2 * e + 1];
        } else {
            const bf16* gp = (const bf16*)graw;
            g0 = (double)b2f(gp[2 * e]); g1 = (double)b2f(gp[2 * e + 1]);
        }
        out[WOFF + e] = ((L + g1) > g0) ? 1.0f : 0.0f;
        out[LOFF + e] = (float)L;
    }
}

// ---------- sparse agg gather: ballot-compaction + float2 packing + unroll-4 ----------
__global__ __launch_bounds__(256) void agg_gather_k(const int* __restrict__ offs,
                                                    const int* __restrict__ entc,
                                                    const int* __restrict__ ente,
                                                    const float* __restrict__ w,
                                                    const float* __restrict__ hb,
                                                    float* __restrict__ aggF) {
    __shared__ int selBuf[4][64];
    int wv = (blockIdx.x * 256 + threadIdx.x) >> 6;
    int lane = threadIdx.x & 63;
    int wloc = (threadIdx.x >> 6);
    if (wv >= NN) return;
    int* sel = selBuf[wloc];
    const int s0 = offs[wv], s1 = offs[wv + 1];
    double a0 = 0.0, a1 = 0.0;
    for (int base = s0; base < s1; base += 64) {
        int i = base + lane;
        int c = 0;
        bool keep = false;
        if (i < s1) {
            c = entc[i];
            keep = w[ente[i]] > 0.5f;
        }
        unsigned long long m = __ballot(keep);
        int cnt = __popcll(m);
        if (keep) {
            int pos = __popcll(m & ((1ULL << lane) - 1ULL));
            sel[pos] = c;
        }
        __builtin_amdgcn_wave_barrier();
        int j = 0;
        for (; j + 4 <= cnt; j += 4) {
            int cA = sel[j], cB = sel[j + 1], cC = sel[j + 2], cD = sel[j + 3];
            float2 hA = *(const float2*)&hb[(size_t)cA * ND + 2 * lane];
            float2 hB = *(const float2*)&hb[(size_t)cB * ND + 2 * lane];
            float2 hC = *(const float2*)&hb[(size_t)cC * ND + 2 * lane];
            float2 hD = *(const float2*)&hb[(size_t)cD * ND + 2 * lane];
            a0 += (double)hA.x; a1 += (double)hA.y;
            a0 += (double)hB.x; a1 += (double)hB.y;
            a0 += (double)hC.x; a1 += (double)hC.y;
            a0 += (double)hD.x; a1 += (double)hD.y;
        }
        for (; j < cnt; ++j) {
            int c2 = sel[j];
            float2 hv = *(const float2*)&hb[(size_t)c2 * ND + 2 * lane];
            a0 += (double)hv.x; a1 += (double)hv.y;
        }
        __builtin_amdgcn_wave_barrier();
    }
    float2 o = make_float2((float)a0, (float)a1);
    *(float2*)&aggF[(size_t)wv * ND + 2 * lane] = o;
}

// ---------- log-softmax (fp32) ----------
__global__ __launch_bounds__(256) void logsoftmax_k(const float* __restrict__ Y,
                                                    float* __restrict__ out) {
    int wid = (blockIdx.x * 256 + threadIdx.x) / 64;
    int lane = threadIdx.x & 63;
    if (wid >= NN) return;
    float v = (lane < NOUT) ? Y[(size_t)wid * NOUT + lane] : -1e30f;
    float m = v;
#pragma unroll
    for (int off = 32; off > 0; off >>= 1) {
        float o = __shfl_xor(m, off, 64);
        m = m > o ? m : o;
    }
    float ex = (lane < NOUT) ? expf(v - m) : 0.0f;
    float s = ex;
#pragma unroll
    for (int off = 32; off > 0; off >>= 1) s += __shfl_xor(s, off, 64);
    if (lane < NOUT) out[(size_t)wid * NOUT + lane] = v - m - logf(s);
}

extern "C" void kernel_launch(void* const* d_in, const int* in_sizes, int n_in,
                              void* d_out, int out_size, void* d_ws, size_t ws_size,
                              hipStream_t stream) {
    float* out = (float*)d_out;

    static const int EXPS[NIN] = {
        NN * 128, 2 * NE, 2 * NE, 16384, 128, 16384, 128, 128, 128, 128, 128,
        16384, 128, 128, 128, 128, 128, 16384, 64, 64, 1, 8192, 64, 64, 64, 2560, 40 };
    if (n_in != NIN) { sent_k<<<1, 1, 0, stream>>>(out, 700.0f); return; }
    if (out_size != NN * NOUT + 2 * NE) { sent_k<<<1, 1, 0, stream>>>(out, 600.0f); return; }
    for (int i = 0; i < NIN; ++i)
        if (in_sizes[i] != EXPS[i]) {
            sent_k<<<1, 1, 0, stream>>>(out, 1000.0f + 128.0f * i);
            return;
        }

    // ---- workspace layout ----
    char* W = (char*)d_ws;
    double* a_src = (double*)W;                      W += (size_t)NN * NH * 8;
    double* a_dst = (double*)W;                      W += (size_t)NN * NH * 8;
    double* stats = (double*)W;                      W += 256 * 8;
    unsigned long long* keyM = (unsigned long long*)W; W += 16 * 8;
    float2* ss = (float2*)W;                         W += 128 * 8;
    float* F1 = (float*)W;                           W += (size_t)NN * ND * 4;
    float* F2 = (float*)W;                           W += (size_t)NN * ND * 4;
    float* F3 = (float*)W;                           W += (size_t)NN * ND * 4;
    float* F4 = (float*)W;                           W += (size_t)NN * ND * 4;
    float* expv = (float*)W;                         W += (size_t)NA * NH * 4;
    float* wa = (float*)W;
    int off = 0;
    float* aW_res = wa + off; off += 16384;
    float* ab_res = wa + off; off += 128;
    float* aWg1 = wa + off; off += 16384;
    float* aas1 = wa + off; off += 128;
    float* aad1 = wa + off; off += 128;
    float* ag1  = wa + off; off += 128;
    float* abe1 = wa + off; off += 128;
    float* aWg2 = wa + off; off += 16384;
    float* aas2 = wa + off; off += 128;
    float* aad2 = wa + off; off += 128;
    float* ag2  = wa + off; off += 128;
    float* abe2 = wa + off; off += 128;
    float* aWs1 = wa + off; off += 16384;
    float* abs1 = wa + off; off += 64;
    float* aWs2 = wa + off; off += 64;
    float* abs2 = wa + off; off += 4;
    float* aWc1 = wa + off; off += 8192;
    float* abc1 = wa + off; off += 64;
    float* agc  = wa + off; off += 64;
    float* abec = wa + off; off += 64;
    float* aWc2 = wa + off; off += 2560;
    float* abc2 = wa + off; off += 40;
    float* aWs1f = wa + off; off += 16384;
    off = (off + 3) & ~3;                            // 16B-align the bf16 plane region
    ushort* wb = (ushort*)(wa + off); off += 110592; // 5 matrices x 3 bf16 planes
    W = (char*)(wa + off);
    int* ei    = (int*)W;  W += (size_t)2 * NE * 4;
    int* offsG = (int*)W;  W += (size_t)(NN + 1) * 4;
    int* curG  = (int*)W;  W += (size_t)NN * 4;
    int* entG  = (int*)W;  W += (size_t)NA * 4;
    int* entD  = (int*)W;  W += (size_t)NA * 4;
    int* offsR = (int*)W;  W += (size_t)(NN + 1) * 4;
    int* curR  = (int*)W;  W += (size_t)NN * 4;
    int* entRc = (int*)W;  W += (size_t)NE * 4;
    int* entRe = (int*)W;  W += (size_t)NE * 4;
    int* bsums = (int*)W;  W += 260 * 4;
    int* flags = (int*)W;  W += 32 * 4;
    int* errflag = (int*)W; W += 4;
    if ((size_t)(W - (char*)d_ws) > ws_size) { sent_k<<<1, 1, 0, stream>>>(out, 900.0f); return; }

    const int NB = ceil_div(NN, 256);

    // ---- 0) detect & convert ----
    Ptrs P;
    for (int i = 0; i < NIN; ++i) { P.p[i] = d_in[i]; P.n[i] = in_sizes[i]; }
    detect_k<<<NIN, 64, 0, stream>>>(P, flags);
    conv_i_k<<<ceil_div(2 * NE, 256), 256, 0, stream>>>(d_in[1], flags, ei, 2 * NE);
    conv_f_k<<<ceil_div(NN * 128, 256), 256, 0, stream>>>(d_in[0], flags, 0, F2, NN * 128);
    {
        ConvTab T;
        struct { int idx; float* dst; int n; } convs[NCV] = {
            {3, aW_res, 16384}, {4, ab_res, 128}, {5, aWg1, 16384}, {6, aas1, 128},
            {7, aad1, 128}, {9, ag1, 128}, {10, abe1, 128}, {11, aWg2, 16384},
            {12, aas2, 128}, {13, aad2, 128}, {15, ag2, 128}, {16, abe2, 128},
            {17, aWs1, 16384}, {18, abs1, 64}, {19, aWs2, 64}, {20, abs2, 1},
            {21, aWc1, 8192}, {22, abc1, 64}, {23, agc, 64}, {24, abec, 64},
            {25, aWc2, 2560}, {26, abc2, 40},
        };
        for (int i = 0; i < NCV; ++i) {
            T.src[i] = convs[i].idx;
            T.dstOff[i] = (int)(convs[i].dst - wa);
            T.n[i] = convs[i].n;
        }
        conv_all_k<<<NCV, 256, 0, stream>>>(P, T, flags, wa);
    }
    repack_ws1_k<<<ceil_div(16384, 256), 256, 0, stream>>>(aWs1, aWs1f);
    {
        SplitTab T5;
        T5.srcOff[0] = (int)(aW_res - wa); T5.n[0] = 16384; T5.dstOff[0] = 0;
        T5.srcOff[1] = (int)(aWg1 - wa);   T5.n[1] = 16384; T5.dstOff[1] = 49152;
        T5.srcOff[2] = (int)(aWg2 - wa);   T5.n[2] = 16384; T5.dstOff[2] = 98304;
        T5.srcOff[3] = (int)(aWs1f - wa);  T5.n[3] = 16384; T5.dstOff[3] = 147456;
        T5.srcOff[4] = (int)(aWc1 - wa);   T5.n[4] = 8192;  T5.dstOff[4] = 196608;
        split_w_k<<<ceil_div(73728, 256), 256, 0, stream>>>(wa, T5, wb);
    }
    hipMemsetAsync(errflag, 0, 4, stream);
    check_k<<<ceil_div(2 * NE, 256), 256, 0, stream>>>(ei, errflag);

    // ---- CSR builds ----
    hipMemsetAsync(curG, 0, (size_t)NN * 4, stream);
    deg_dst_k<<<ceil_div(NA, 256), 256, 0, stream>>>(ei, curG);
    scan1_k<<<NB, 256, 0, stream>>>(curG, offsG, bsums, NN);
    scan2_k<<<1, 256, 0, stream>>>(bsums, NB);
    scan3_k<<<ceil_div(NN + 1, 256), 256, 0, stream>>>(offsG, bsums, NN, NB);
    copy_k<<<ceil_div(NN, 256), 256, 0, stream>>>(offsG, curG, NN);
    scat_dst_k<<<ceil_div(NA, 256), 256, 0, stream>>>(ei, curG, entG, entD);

    hipMemsetAsync(curR, 0, (size_t)NN * 4, stream);
    deg_row_k<<<ceil_div(NE, 256), 256, 0, stream>>>(ei, curR);
    scan1_k<<<NB, 256, 0, stream>>>(curR, offsR, bsums, NN);
    scan2_k<<<1, 256, 0, stream>>>(bsums, NB);
    scan3_k<<<ceil_div(NN + 1, 256), 256, 0, stream>>>(offsR, bsums, NN, NB);
    copy_k<<<ceil_div(NN, 256), 256, 0, stream>>>(offsR, curR, NN);
    scat_row_k<<<ceil_div(NE, 256), 256, 0, stream>>>(ei, curR, entRc, entRe);

    const int NTIL = ceil_div(NN, 64);     // 64-row tiles, grid-strided
    const int GB = 512;                    // 2 blocks/CU (53 KB LDS each)
    const size_t SHB = (size_t)3 * 64 * 136 * 2 + 128 * 8 + 2 * 4 * 16 * 8;  // 54272 B

    // ---- 1) x_proj ----
    gemm_bf16_k<128, 64, false, 0, false><<<GB, 512, SHB, stream>>>(
        F2, nullptr, nullptr, wb + 0, ab_res, F1, NN, NTIL,
        nullptr, nullptr, nullptr, nullptr, nullptr);

    // ---- GAT layer 1 (att scores fused into GEMM epilogue) ----
    hipMemsetAsync(keyM, 0, 16 * 8, stream);
    gemm_bf16_k<128, 64, false, 0, true><<<GB, 512, SHB, stream>>>(
        F1, nullptr, nullptr, wb + 49152, nullptr, F2, NN, NTIL,
        aas1, aad1, a_src, a_dst, keyM);
    edge_exp_k<<<ceil_div(NA * NH, 256), 256, 0, stream>>>(entG, entD, a_src, a_dst, keyM, expv);
    gat_gather_k<<<ceil_div(NN * 64, 256), 256, 0, stream>>>(offsG, entG, F2, expv, F4);
    hipMemsetAsync(stats, 0, 2 * ND * 8, stream);
    bn_stats1_k<128><<<ceil_div(NN, 256), 256, 0, stream>>>(F4, stats, 256);
    bn_fin_k<128><<<1, 128, 0, stream>>>(stats, ag1, abe1, ss);

    // ---- GAT layer 2 (BN1+ELU fused into X staging; att fused in epilogue) ----
    hipMemsetAsync(keyM, 0, 16 * 8, stream);
    gemm_bf16_k<128, 64, false, 1, true><<<GB, 512, SHB, stream>>>(
        F4, nullptr, ss, wb + 98304, nullptr, F2, NN, NTIL,
        aas2, aad2, a_src, a_dst, keyM);
    edge_exp_k<<<ceil_div(NA * NH, 256), 256, 0, stream>>>(entG, entD, a_src, a_dst, keyM, expv);
    gat_gather_k<<<ceil_div(NN * 64, 256), 256, 0, stream>>>(offsG, entG, F2, expv, F4);
    hipMemsetAsync(stats, 0, 2 * ND * 8, stream);
    bn_stats1_k<128><<<ceil_div(NN, 256), 256, 0, stream>>>(F4, stats, 256);
    bn_fin_k<128><<<1, 128, 0, stream>>>(stats, ag2, abe2, ss);
    bn_apply_ss_k<128, 0><<<ceil_div(NN * ND, 256), 256, 0, stream>>>(F4, ss, F3);  // h_base

    // ---- fused pr|pc gemm ----
    gemm_bf16_k<128, 64, false, 0, false><<<GB, 512, SHB, stream>>>(
        F3, nullptr, nullptr, wb + 147456, nullptr, F2, NN, NTIL,
        nullptr, nullptr, nullptr, nullptr, nullptr);

    // ---- edge logits (flat: coalesced writes) ----
    edge_logits_k<<<ceil_div(NE * 16, 256), 256, 0, stream>>>(
        ei, (const float4*)F2, (const float4*)abs1, (const float4*)aWs2, abs2, d_in[2], flags,
        out);

    // ---- agg (ballot-compacted gather) -> F1 ----
    agg_gather_k<<<ceil_div(NN * 64, 256), 256, 0, stream>>>(offsR, entRc, entRe, out + WOFF,
                                                             F3, F1);

    // ---- t = (h_base + agg) @ Wc1.T + bc1 ----
    gemm_bf16_k<64, 64, true, 0, false><<<GB, 512, SHB, stream>>>(
        F3, F1, nullptr, wb + 196608, abc1, F4, NN, NTIL,
        nullptr, nullptr, nullptr, nullptr, nullptr);

    hipMemsetAsync(stats, 0, 2 * NHID * 8, stream);
    bn_stats1_k<64><<<ceil_div(NN, 256), 256, 0, stream>>>(F4, stats, 256);
    bn_fin_k<64><<<1, 64, 0, stream>>>(stats, agc, abec, ss);

    // ---- logits (BN+ReLU fused into X staging) ----
    float* logits = F4 + (size_t)NN * NHID;
    gemm_k<40, 64, 10, false, 2, false><<<ceil_div(NN, 100), 256, 0, stream>>>(
        F4, nullptr, ss, aWc2, 64, abc2, logits, NN,
        nullptr, nullptr, nullptr, nullptr, nullptr);

    logsoftmax_k<<<ceil_div(NN * 64, 256), 256, 0, stream>>>(logits, out);

    finalize_k<<<1, 1, 0, stream>>>(errflag, out);
}